// Round 15
// baseline (70.040 us; speedup 1.0000x reference)
//
#include <hip/hip_runtime.h>
#include <stdint.h>

// TopKLayer quirky sparse_hw: per row (3136 elems), t = spatial index of the
// k-th largest |x| (k=313, ties ascending index); keep the t smallest-|x|
// elements (stable). 256-THREAD BLOCK PER ROW = R12's lean structure with the
// row's register footprint halved (13 words/thread) so total VGPR+AGPR fits
// the 85-reg budget of launch_bounds(256,6) -> 6 waves/SIMD (R12's reg-row at
// 128t was pinned to 4/SIMD by ~128 total regs incl AGPR parking).

#define HW    3136
#define NT    256
#define KSEL  313u
#define CAP   320u       // candidate bin capacity (stat max ~190)
#define CAP2  64u        // tie-set capacity
#define M31   0x7fffffffu
#define SENT  0xFFFFFFFFu

// LDS layout (words)
#define O_H    0         // 1088 = 1024 packed-u16 words + pad every 16
#define O_CAND 1088      // 320
#define O_HC   1408      // 256
#define O_TINY 1664      // 64
#define LDSW   1728      // 6912 B

__device__ __forceinline__ unsigned wscan_incl(unsigned v) {
    const int lane = threadIdx.x & 63;
#pragma unroll
    for (int d = 1; d < 64; d <<= 1) {
        unsigned o = __shfl_up(v, d, 64);
        if (lane >= d) v += o;
    }
    return v;
}

__device__ __forceinline__ unsigned bcast_first(unsigned flag, unsigned val) {
    unsigned long long bal = __ballot(flag != 0);
    if (!bal) return 0u;
    return __shfl(val, __ffsll(bal) - 1, 64);
}

// packed u16 histogram with pad-every-16-words addressing
__device__ __forceinline__ void hadd(unsigned* h, unsigned b) {
    const unsigned w = b >> 1;
    atomicAdd(&h[w + (w >> 4)], (b & 1) ? 0x10000u : 1u);
}

// Wave0-only finish: 256-bin subhist over candidates, locate, tie-rank.
// hc must be pre-zeroed. Returns composite (low20<<12)|idx, or SENT, or 0.
template <bool fromTop>
__device__ unsigned wave_finish(unsigned* lds, unsigned m1, unsigned cnt) {
    const int lane = threadIdx.x & 63;
    unsigned* cand = lds + O_CAND;
    unsigned* hc   = lds + O_HC;
    unsigned* tiny = lds + O_TINY;
    if (m1 == 0) return 0u;
    if (cnt > CAP) return SENT;
    for (unsigned i = lane; i < cnt; i += 64) atomicAdd(&hc[cand[i] >> 24], 1u);
    unsigned hh[4];
#pragma unroll
    for (int i = 0; i < 4; ++i) hh[i] = hc[4 * lane + i];
    const unsigned s4 = hh[0] + hh[1] + hh[2] + hh[3];
    unsigned run2 = wscan_incl(s4) - s4;
    unsigned packed2 = 0;
#pragma unroll
    for (int i = 0; i < 4; ++i) {
        if (fromTop) {
            const unsigned suf = cnt - run2 - hh[i];
            if (suf < m1 && m1 <= suf + hh[i])
                packed2 = ((unsigned)(4 * lane + i) << 16) | (m1 - suf);
        } else {
            if (run2 < m1 && m1 <= run2 + hh[i])
                packed2 = ((unsigned)(4 * lane + i) << 16) | (m1 - run2);
        }
        run2 += hh[i];
    }
    packed2 = bcast_first(packed2, packed2);
    if (packed2 == 0) return 0u;
    const unsigned b2 = packed2 >> 16;
    const unsigned m2 = packed2 & 0xFFFFu;
    unsigned tc = 0;
    for (unsigned i = lane; i < cnt; i += 64) tc += ((cand[i] >> 24) == b2);
    const unsigned tincl = wscan_incl(tc);
    const unsigned c2 = __shfl((int)tincl, 63, 64);
    if (c2 > CAP2) return SENT;
    unsigned tpos = tincl - tc;
    for (unsigned i = lane; i < cnt; i += 64) {
        const unsigned cw = cand[i];
        if ((cw >> 24) == b2) tiny[tpos++] = cw;
    }
    unsigned hitf = 0, resv = 0;
    if ((unsigned)lane < c2) {
        const unsigned ci = tiny[lane];
        const unsigned di = fromTop ? (ci ^ 0xFFFu) : ci;
        unsigned r = 1;
        for (unsigned j = 0; j < c2; ++j) {
            const unsigned dj = fromTop ? (tiny[j] ^ 0xFFFu) : tiny[j];
            if (fromTop ? (dj > di) : (dj < di)) r++;
        }
        if (r == m2) { hitf = 1; resv = ci; }
    }
    return bcast_first(hitf, resv);
}

// Pathological fallback: bin-filtered counting rank over global row.
template <bool fromTop>
__device__ void block_fallback(const unsigned* __restrict__ gx,
                               unsigned b0, unsigned m1, unsigned* res) {
    const int t = threadIdx.x;
    for (int j = t; j < HW; j += NT) {
        const unsigned k = gx[j] & M31;
        if ((k >> 20) != b0) continue;
        unsigned Ci = ((k & 0xFFFFFu) << 12) | (unsigned)j;
        if (fromTop) Ci ^= 0xFFFu;
        unsigned r = 1;
        for (int j2 = 0; j2 < HW; ++j2) {
            const unsigned k2 = gx[j2] & M31;
            if ((k2 >> 20) != b0) continue;
            unsigned Cj = ((k2 & 0xFFFFFu) << 12) | (unsigned)j2;
            if (fromTop) Cj ^= 0xFFFu;
            if (fromTop ? (Cj > Ci) : (Cj < Ci)) r++;
        }
        if (r == m1) res[0] = ((k & 0xFFFFFu) << 12) | (unsigned)j;
    }
}

extern "C" __global__ void __launch_bounds__(NT, 6)
topk_kernel(const float* __restrict__ x, float* __restrict__ out) {
    __shared__ unsigned lds[LDSW];
    __shared__ unsigned s_warp[4];
    __shared__ unsigned s_b[4];   // [0]=bin [1]=m1 [2]=result [3]=counter

    const int t = threadIdx.x;
    const int lane = t & 63;
    const int wid = t >> 6;
    const size_t row = blockIdx.x;
    const uint4* __restrict__ xin = (const uint4*)(x + row * HW);
    uint4* __restrict__ xo = (uint4*)(out + row * HW);
    const unsigned* __restrict__ gx = (const unsigned*)xin;
    const uint4 z4 = make_uint4(0u, 0u, 0u, 0u);
    const bool tail = (t < 16);

    // load row into registers (13 words/thread); fence blocks remat-as-reload
    uint4 v0 = xin[t];
    uint4 v1 = xin[t + NT];
    uint4 v2 = xin[t + 2 * NT];
    uint4 vt = tail ? xin[768 + t] : z4;
    asm volatile("" : "+v"(v0.x), "+v"(v0.y), "+v"(v0.z), "+v"(v0.w));
    asm volatile("" : "+v"(v1.x), "+v"(v1.y), "+v"(v1.z), "+v"(v1.w));
    asm volatile("" : "+v"(v2.x), "+v"(v2.y), "+v"(v2.z), "+v"(v2.w));
    asm volatile("" : "+v"(vt.x), "+v"(vt.y), "+v"(vt.z), "+v"(vt.w));

    // P0: clear hist (1088 words = 272 uint4)
    {
        uint4* h4 = (uint4*)(lds + O_H);
        h4[t] = z4;
        if (tail) h4[NT + t] = z4;
    }
    __syncthreads();                                         // B1

    // P1: histogram from registers (abs bits 30:20)
    hadd(lds, (v0.x & M31) >> 20); hadd(lds, (v0.y & M31) >> 20);
    hadd(lds, (v0.z & M31) >> 20); hadd(lds, (v0.w & M31) >> 20);
    hadd(lds, (v1.x & M31) >> 20); hadd(lds, (v1.y & M31) >> 20);
    hadd(lds, (v1.z & M31) >> 20); hadd(lds, (v1.w & M31) >> 20);
    hadd(lds, (v2.x & M31) >> 20); hadd(lds, (v2.y & M31) >> 20);
    hadd(lds, (v2.z & M31) >> 20); hadd(lds, (v2.w & M31) >> 20);
    if (tail) {
        hadd(lds, (vt.x & M31) >> 20); hadd(lds, (vt.y & M31) >> 20);
        hadd(lds, (vt.z & M31) >> 20); hadd(lds, (vt.w & M31) >> 20);
    }
    __syncthreads();                                         // B2

    // P2: pull packed counts (thread t owns bins 8t..8t+7 = words 4t..4t+3,
    // padded addr 4t + (t>>2) + j); wave scan + cross-wave publish
    unsigned cpk[4];
    {
        const unsigned a0 = 4u * (unsigned)t + ((unsigned)t >> 2);
#pragma unroll
        for (int j = 0; j < 4; ++j) cpk[j] = lds[O_H + a0 + j];
    }
    unsigned ssum = 0;
#pragma unroll
    for (int j = 0; j < 4; ++j) ssum += (cpk[j] & 0xFFFFu) + (cpk[j] >> 16);
    const unsigned Si = wscan_incl(ssum);
    if (lane == 63) s_warp[wid] = Si;
    __syncthreads();                                         // B3

    // P3: base; locate A (register CDF); zero counter; clear hc
    unsigned cross = 0;
    for (int w2 = 0; w2 < wid; ++w2) cross += s_warp[w2];
    const unsigned base = cross + Si - ssum;   // excl CDF of bin 8t
    {
        unsigned run = base;
#pragma unroll
        for (int j = 0; j < 4; ++j) {
            const unsigned lo = cpk[j] & 0xFFFFu, hi = cpk[j] >> 16;
            unsigned suf = HW - run - lo;
            if (suf < KSEL && KSEL <= suf + lo) { s_b[0] = 8u * t + 2u * j; s_b[1] = KSEL - suf; }
            run += lo;
            suf = HW - run - hi;
            if (suf < KSEL && KSEL <= suf + hi) { s_b[0] = 8u * t + 2u * j + 1u; s_b[1] = KSEL - suf; }
            run += hi;
        }
    }
    if (t == 0) s_b[3] = 0;
    lds[O_HC + t] = 0;
    __syncthreads();                                         // B4

    // P4: compact A from registers
    auto compact_regs = [&](unsigned b0) {
        auto cput = [&](unsigned wv, unsigned idx) {
            const unsigned k = wv & M31;
            if ((k >> 20) == b0) {
                const unsigned p = atomicAdd(&s_b[3], 1u);
                if (p < CAP) lds[O_CAND + p] = ((k & 0xFFFFFu) << 12) | idx;
            }
        };
        unsigned i0 = 4u * (unsigned)t;
        cput(v0.x, i0); cput(v0.y, i0 + 1u); cput(v0.z, i0 + 2u); cput(v0.w, i0 + 3u);
        i0 = 4u * (unsigned)(t + NT);
        cput(v1.x, i0); cput(v1.y, i0 + 1u); cput(v1.z, i0 + 2u); cput(v1.w, i0 + 3u);
        i0 = 4u * (unsigned)(t + 2 * NT);
        cput(v2.x, i0); cput(v2.y, i0 + 1u); cput(v2.z, i0 + 2u); cput(v2.w, i0 + 3u);
        if (tail) {
            i0 = 4u * (unsigned)(768 + t);
            cput(vt.x, i0); cput(vt.y, i0 + 1u); cput(vt.z, i0 + 2u); cput(vt.w, i0 + 3u);
        }
    };
    const unsigned b0A = s_b[0];
    const unsigned m1A = s_b[1];
    compact_regs(b0A);
    __syncthreads();                                         // B5

    // P5: wave0 finish A
    if (wid == 0) {
        const unsigned r = wave_finish<true>(lds, m1A, s_b[3]);
        if (lane == 0) s_b[2] = r;
    }
    __syncthreads();                                         // B6
    unsigned compA = s_b[2];
    if (compA == SENT) {
        block_fallback<true>(gx, b0A, m1A, &s_b[2]);
        __syncthreads();
        compA = s_b[2];
    }
    const unsigned tIdx = compA & 0xFFFu;

    // P6: locate B (cpk still live); zero counter; clear hc; sentinel
    {
        unsigned run = base;
#pragma unroll
        for (int j = 0; j < 4; ++j) {
            const unsigned lo = cpk[j] & 0xFFFFu, hi = cpk[j] >> 16;
            if (run < tIdx && tIdx <= run + lo) { s_b[0] = 8u * t + 2u * j; s_b[1] = tIdx - run; }
            run += lo;
            if (run < tIdx && tIdx <= run + hi) { s_b[0] = 8u * t + 2u * j + 1u; s_b[1] = tIdx - run; }
            run += hi;
        }
    }
    if (t == 0) {
        s_b[3] = 0;
        if (tIdx == 0) { s_b[0] = 0; s_b[1] = 0; }   // keep-nothing (benign)
    }
    lds[O_HC + t] = 0;
    __syncthreads();                                         // B7

    // P7: compact B from registers
    const unsigned b0B = s_b[0];
    const unsigned m1B = s_b[1];
    compact_regs(b0B);
    __syncthreads();                                         // B8

    // P8: wave0 finish B
    if (wid == 0) {
        const unsigned r = wave_finish<false>(lds, m1B, s_b[3]);
        if (lane == 0) s_b[2] = r;
    }
    __syncthreads();                                         // B9
    unsigned compB = s_b[2];
    if (compB == SENT) {
        block_fallback<false>(gx, b0B, m1B, &s_b[2]);
        __syncthreads();
        compB = s_b[2];
    }
    const unsigned KB = (b0B << 20) | (compB >> 12);
    const unsigned eB = compB & 0xFFFu;

    // P9: mask + store from registers: keep = k < KB || (k == KB && idx <= eB)
    {
        auto msk = [&](unsigned wv, unsigned idx) -> unsigned {
            const unsigned k = wv & M31;
            return (k < KB || (k == KB && idx <= eB)) ? wv : 0u;
        };
        uint4 o;
        unsigned i0 = 4u * (unsigned)t;
        o.x = msk(v0.x, i0); o.y = msk(v0.y, i0 + 1u);
        o.z = msk(v0.z, i0 + 2u); o.w = msk(v0.w, i0 + 3u);
        xo[t] = o;
        i0 = 4u * (unsigned)(t + NT);
        o.x = msk(v1.x, i0); o.y = msk(v1.y, i0 + 1u);
        o.z = msk(v1.z, i0 + 2u); o.w = msk(v1.w, i0 + 3u);
        xo[t + NT] = o;
        i0 = 4u * (unsigned)(t + 2 * NT);
        o.x = msk(v2.x, i0); o.y = msk(v2.y, i0 + 1u);
        o.z = msk(v2.z, i0 + 2u); o.w = msk(v2.w, i0 + 3u);
        xo[t + 2 * NT] = o;
        if (tail) {
            i0 = 4u * (unsigned)(768 + t);
            o.x = msk(vt.x, i0); o.y = msk(vt.y, i0 + 1u);
            o.z = msk(vt.z, i0 + 2u); o.w = msk(vt.w, i0 + 3u);
            xo[768 + t] = o;
        }
    }
}

extern "C" void kernel_launch(void* const* d_in, const int* in_sizes, int n_in,
                              void* d_out, int out_size, void* d_ws, size_t ws_size,
                              hipStream_t stream) {
    const float* x = (const float*)d_in[0];
    float* out = (float*)d_out;
    const int rows = in_sizes[0] / HW;          // 8192
    topk_kernel<<<dim3(rows), dim3(NT), 0, stream>>>(x, out);
}